// Round 1
// baseline (94.897 us; speedup 1.0000x reference)
//
#include <hip/hip_runtime.h>
#include <math.h>

#define BATCH 4096
#define DIM 128
#define NCLS 100
#define MARGIN 0.3f
#define NTILE 272          // upper-triangle 128x256 supertiles
#define GRID_MAIN 528      // 272 pairwise + 256 CE

typedef __attribute__((ext_vector_type(8))) short short8;
typedef __attribute__((ext_vector_type(4))) float f32x4;

// ---- bf16 helpers (bit-level, RNE) ----
__device__ __forceinline__ unsigned short f2bf(float f) {
    unsigned int u = __float_as_uint(f);
    unsigned int r = (u + 0x7FFFu + ((u >> 16) & 1u)) >> 16;
    return (unsigned short)r;
}
__device__ __forceinline__ float bf2f(unsigned short b) {
    return __uint_as_float(((unsigned int)b) << 16);
}

// Order-preserving encodings for NONNEGATIVE floats; identity = 0 under atomic max.
#define ENC_MAX_ID 0x80000000u   /* enc_max(0.0f) */
#define ENC_MIN_ID 0x403FFFFFu   /* enc_min(+inf) */
__device__ __forceinline__ unsigned int enc_max(float v) {
    return (__float_as_uint(v) >> 1) | 0x80000000u;
}
__device__ __forceinline__ float dec_max(unsigned int k) {
    return __uint_as_float((k & 0x7FFFFFFFu) << 1);
}
__device__ __forceinline__ unsigned int enc_min(float v) {
    return 0x7FFFFFFFu - (__float_as_uint(v) >> 1);
}
__device__ __forceinline__ float dec_min(unsigned int k) {
    return __uint_as_float((0x7FFFFFFFu - k) << 1);
}

__device__ __forceinline__ float4 ld4(const float* p) {
    return *reinterpret_cast<const float4*>(p);
}

// convert 8 fp32 -> 8 bf16 (RNE) and return sum of squares of the ROUNDED values
__device__ __forceinline__ short8 cvt8s(float4 f0, float4 f1, float* ss) {
    float v[8] = {f0.x, f0.y, f0.z, f0.w, f1.x, f1.y, f1.z, f1.w};
    short8 r;
    float s = 0.f;
    #pragma unroll
    for (int i = 0; i < 8; ++i) {
        unsigned short b = f2bf(v[i]);
        float y = bf2f(b);
        s += y * y;
        r[i] = (short)b;
    }
    *ss = s;
    return r;
}
__device__ __forceinline__ short8 cvt8n(float4 f0, float4 f1) {
    float v[8] = {f0.x, f0.y, f0.z, f0.w, f1.x, f1.y, f1.z, f1.w};
    short8 r;
    #pragma unroll
    for (int i = 0; i < 8; ++i) r[i] = (short)f2bf(v[i]);
    return r;
}

// FRAGMENT MAPPING (same as the old frag-major ebf layout, now computed inline):
//   A-frag j of 16-row group: lane l holds rows base+(l&15), dims j*32+(l>>4)*8 .. +7
//   B-tile LDS short s=t*8  : col cbase+ct*16+(t&15), dims (t>>4)*8 .. +7
//   W-frag j of tile t      : cls t*16+(l&15),        dims j*32+(l>>4)*8 .. +7

// Fused kernel: blocks 0..271  -> pairwise supertiles (on-the-fly bf16 conversion,
//                                 double-buffered LDS B staging, in-kernel sq);
//               blocks 272..527 -> CE per 16 rows (on-the-fly A/W conversion).
// Fence-free encoded-atomic fan-in; last block reduces + writes out[0].
// Fan state (ticket, ce_sum, maxk, mink) zeroed by a hipMemsetAsync node.
__global__ __launch_bounds__(256) void fused_kernel(
        const float* __restrict__ emb, const int* __restrict__ labels,
        const float* __restrict__ fcw, const float* __restrict__ fcb,
        unsigned int* __restrict__ maxk, unsigned int* __restrict__ mink,
        float* __restrict__ ce_sum, int* __restrict__ ticket,
        float* __restrict__ out) {
    __shared__ float lg[16][128];
    __shared__ unsigned int colk[512];           // [0..255] col-max, [256..511] col-min
    __shared__ unsigned short bstage[2][2048];   // 2 x 4KB bf16 B-tiles
    __shared__ float colsqw[16][4][16];          // per-tile, per-wave col-sq partials
    __shared__ int lastFlag;
    int bid = blockIdx.x, tid = threadIdx.x;
    int wave = tid >> 6, lane = tid & 63;
    int lm = lane & 15, lq = lane >> 4;

    if (bid < NTILE) {
        // ---- map bid -> (rowgrp, chunk): chunk c admits rowgrps 0..2c+1 ----
        int c = 0, rem = bid;
        while (rem >= 2 * c + 2) { rem -= 2 * c + 2; ++c; }
        int rowgrp = rem;          // 0..2c+1 (128-row groups)
        int chunk  = c;            // 256-col chunks

        int rbase = rowgrp * 128 + wave * 32;   // this wave's 32 rows

        // ---- A fragments: convert fp32 -> bf16 in-register, accumulate row sq ----
        short8 a[8];
        float rsq[2] = {0.f, 0.f};
        #pragma unroll
        for (int g = 0; g < 2; ++g) {
            #pragma unroll
            for (int j = 0; j < 4; ++j) {
                const float* p = emb + (rbase + g * 16 + lm) * DIM + j * 32 + lq * 8;
                float ss;
                a[g * 4 + j] = cvt8s(ld4(p), ld4(p + 4), &ss);
                rsq[g] += ss;
            }
        }
        // fold 32-dim partials across the 4 lanes sharing (lane&15) -> full row sq
        #pragma unroll
        for (int g = 0; g < 2; ++g) {
            rsq[g] += __shfl_xor(rsq[g], 16, 64);
            rsq[g] += __shfl_xor(rsq[g], 32, 64);
        }
        // redistribute to the MFMA C-layout rows (row = lq*4 + r)
        float sqr[8];
        int labr[8];
        #pragma unroll
        for (int r = 0; r < 4; ++r) {
            sqr[r]     = __shfl(rsq[0], lq * 4 + r, 64);
            sqr[4 + r] = __shfl(rsq[1], lq * 4 + r, 64);
        }
        #pragma unroll
        for (int g = 0; g < 2; ++g)
            #pragma unroll
            for (int r = 0; r < 4; ++r)
                labr[g * 4 + r] = labels[rbase + g * 16 + lq * 4 + r];

        colk[tid] = 0; colk[256 + tid] = 0;

        float rmax[8], rmin[8];
        #pragma unroll
        for (int r = 0; r < 8; ++r) { rmax[r] = -INFINITY; rmin[r] = INFINITY; }

        int cbase = chunk * 256;
        // B staging source: thread t covers col cbase+ct*16+(t&15), dims (t>>4)*8..+7
        const float* bp = emb + (cbase + (tid & 15)) * DIM + (tid >> 4) * 8;
        float4 f0 = ld4(bp);                    // tile 0 prefetch
        float4 f1 = ld4(bp + 4);

        for (int ct = 0; ct < 16; ++ct) {
            // convert + stage tile ct, publish col-sq partial, prefetch tile ct+1
            float part;
            short8 bv = cvt8s(f0, f1, &part);
            *reinterpret_cast<short8*>(&bstage[ct & 1][tid * 8]) = bv;
            part += __shfl_xor(part, 16, 64);
            part += __shfl_xor(part, 32, 64);
            if (lane < 16) colsqw[ct][wave][lane] = part;
            if (ct < 15) {
                const float* np = bp + (ct + 1) * 16 * DIM;
                f0 = ld4(np);
                f1 = ld4(np + 4);
            }
            __syncthreads();   // also covers colk init on ct=0

            const unsigned short* bb = &bstage[ct & 1][lane * 8];
            short8 b0 = *reinterpret_cast<const short8*>(bb);
            short8 b1 = *reinterpret_cast<const short8*>(bb + 512);
            short8 b2 = *reinterpret_cast<const short8*>(bb + 1024);
            short8 b3 = *reinterpret_cast<const short8*>(bb + 1536);
            // two independent MFMA chains (row-groups 0 and 1)
            f32x4 c0 = {0.f, 0.f, 0.f, 0.f};
            f32x4 c1 = {0.f, 0.f, 0.f, 0.f};
            c0 = __builtin_amdgcn_mfma_f32_16x16x32_bf16(a[0], b0, c0, 0, 0, 0);
            c1 = __builtin_amdgcn_mfma_f32_16x16x32_bf16(a[4], b0, c1, 0, 0, 0);
            c0 = __builtin_amdgcn_mfma_f32_16x16x32_bf16(a[1], b1, c0, 0, 0, 0);
            c1 = __builtin_amdgcn_mfma_f32_16x16x32_bf16(a[5], b1, c1, 0, 0, 0);
            c0 = __builtin_amdgcn_mfma_f32_16x16x32_bf16(a[2], b2, c0, 0, 0, 0);
            c1 = __builtin_amdgcn_mfma_f32_16x16x32_bf16(a[6], b2, c1, 0, 0, 0);
            c0 = __builtin_amdgcn_mfma_f32_16x16x32_bf16(a[3], b3, c0, 0, 0, 0);
            c1 = __builtin_amdgcn_mfma_f32_16x16x32_bf16(a[7], b3, c1, 0, 0, 0);

            int col = cbase + ct * 16 + lm;
            float sqc = (colsqw[ct][0][lm] + colsqw[ct][1][lm]) +
                        (colsqw[ct][2][lm] + colsqw[ct][3][lm]);
            int lc = labels[col];
            float cmax = -INFINITY, cmin = INFINITY;
            #pragma unroll
            for (int r = 0; r < 4; ++r) {
                float v0 = fmaxf(fmaf(c0[r], -2.0f, sqc) + sqr[r], 0.f);
                bool s0 = (lc == labr[r]);
                rmax[r] = s0 ? fmaxf(rmax[r], v0) : rmax[r];
                rmin[r] = s0 ? rmin[r] : fminf(rmin[r], v0);
                cmax    = s0 ? fmaxf(cmax, v0) : cmax;
                cmin    = s0 ? cmin : fminf(cmin, v0);
                float v1 = fmaxf(fmaf(c1[r], -2.0f, sqc) + sqr[4 + r], 0.f);
                bool s1 = (lc == labr[4 + r]);
                rmax[4 + r] = s1 ? fmaxf(rmax[4 + r], v1) : rmax[4 + r];
                rmin[4 + r] = s1 ? rmin[4 + r] : fminf(rmin[4 + r], v1);
                cmax        = s1 ? fmaxf(cmax, v1) : cmax;
                cmin        = s1 ? cmin : fminf(cmin, v1);
            }
            // fold this wave's 32 rows into the 16 cols (combine lq groups)
            cmax = fmaxf(cmax, __shfl_xor(cmax, 16, 64));
            cmax = fmaxf(cmax, __shfl_xor(cmax, 32, 64));
            cmin = fminf(cmin, __shfl_xor(cmin, 16, 64));
            cmin = fminf(cmin, __shfl_xor(cmin, 32, 64));
            if (lq == 0) {   // 16 lanes, 16 distinct banks -> conflict-free ds atomics
                atomicMax(&colk[ct * 16 + lm], enc_max(fmaxf(cmax, 0.f)));
                atomicMax(&colk[256 + ct * 16 + lm], enc_min(fmaxf(cmin, 0.f)));
            }
        }
        // row reduce across the 16 col-slots
        #pragma unroll
        for (int off = 1; off < 16; off <<= 1) {
            #pragma unroll
            for (int r = 0; r < 8; ++r) {
                rmax[r] = fmaxf(rmax[r], __shfl_xor(rmax[r], off, 64));
                rmin[r] = fminf(rmin[r], __shfl_xor(rmin[r], off, 64));
            }
        }
        if (lm == 0) {
            #pragma unroll
            for (int g = 0; g < 2; ++g)
                #pragma unroll
                for (int r = 0; r < 4; ++r) {
                    int row = rbase + g * 16 + lq * 4 + r;
                    unsigned int kx = enc_max(fmaxf(rmax[g * 4 + r], 0.f));
                    unsigned int kn = enc_min(fmaxf(rmin[g * 4 + r], 0.f));
                    if (kx != ENC_MAX_ID)
                        __hip_atomic_fetch_max(&maxk[row], kx,
                                               __ATOMIC_RELAXED, __HIP_MEMORY_SCOPE_AGENT);
                    if (kn != ENC_MIN_ID)
                        __hip_atomic_fetch_max(&mink[row], kn,
                                               __ATOMIC_RELAXED, __HIP_MEMORY_SCOPE_AGENT);
                }
        }
        __syncthreads();
        // column publish: one thread per col
        {
            unsigned int kx = colk[tid], kn = colk[256 + tid];
            int col = cbase + tid;
            if (kx > ENC_MAX_ID)       // >: skip identity AND the harmless enc_max(0)
                __hip_atomic_fetch_max(&maxk[col], kx,
                                       __ATOMIC_RELAXED, __HIP_MEMORY_SCOPE_AGENT);
            if (kn != 0 && kn != ENC_MIN_ID)
                __hip_atomic_fetch_max(&mink[col], kn,
                                       __ATOMIC_RELAXED, __HIP_MEMORY_SCOPE_AGENT);
        }
    } else {
        // ---------------- cross-entropy ----------------
        int R0 = (bid - NTILE) * 16;
        lg[tid >> 4][112 + (tid & 15)] = -INFINITY;   // pad cols 112..127

        const float* apx = emb + (R0 + lm) * DIM + lq * 8;
        short8 a0 = cvt8n(ld4(apx),      ld4(apx + 4));
        short8 a1 = cvt8n(ld4(apx + 32), ld4(apx + 36));
        short8 a2 = cvt8n(ld4(apx + 64), ld4(apx + 68));
        short8 a3 = cvt8n(ld4(apx + 96), ld4(apx + 100));

        for (int t = wave * 2; t < 7 && t < wave * 2 + 2; ++t) {
            int cls = t * 16 + lm;
            short8 b0, b1, b2, b3;
            if (cls < NCLS) {
                const float* wp = fcw + cls * DIM + lq * 8;
                b0 = cvt8n(ld4(wp),      ld4(wp + 4));
                b1 = cvt8n(ld4(wp + 32), ld4(wp + 36));
                b2 = cvt8n(ld4(wp + 64), ld4(wp + 68));
                b3 = cvt8n(ld4(wp + 96), ld4(wp + 100));
            } else {
                short8 z = {0, 0, 0, 0, 0, 0, 0, 0};
                b0 = z; b1 = z; b2 = z; b3 = z;
            }
            f32x4 cacc4 = {0.f, 0.f, 0.f, 0.f};
            cacc4 = __builtin_amdgcn_mfma_f32_16x16x32_bf16(a0, b0, cacc4, 0, 0, 0);
            cacc4 = __builtin_amdgcn_mfma_f32_16x16x32_bf16(a1, b1, cacc4, 0, 0, 0);
            cacc4 = __builtin_amdgcn_mfma_f32_16x16x32_bf16(a2, b2, cacc4, 0, 0, 0);
            cacc4 = __builtin_amdgcn_mfma_f32_16x16x32_bf16(a3, b3, cacc4, 0, 0, 0);
            float bias = (cls < NCLS) ? fcb[cls] : -INFINITY;
            #pragma unroll
            for (int r = 0; r < 4; ++r)
                lg[lq * 4 + r][t * 16 + lm] = cacc4[r] + bias;
        }
        __syncthreads();
        float cacc = 0.f;
        #pragma unroll
        for (int i = 0; i < 4; ++i) {
            int r = wave * 4 + i;
            float x0 = lg[r][lane], x1 = lg[r][lane + 64];
            float m = fmaxf(x0, x1);
            #pragma unroll
            for (int off = 1; off < 64; off <<= 1) m = fmaxf(m, __shfl_xor(m, off, 64));
            float s = expf(x0 - m) + expf(x1 - m);    // -inf pads -> 0
            #pragma unroll
            for (int off = 1; off < 64; off <<= 1) s += __shfl_xor(s, off, 64);
            if (lane == 0) {
                int lab = labels[R0 + r];
                cacc += (m + logf(s)) - lg[r][lab];
            }
        }
        __syncthreads();
        if (lane == 0) lg[0][wave] = cacc;
        __syncthreads();
        if (tid == 0) {
            float bsum = lg[0][0] + lg[0][1] + lg[0][2] + lg[0][3];
            __hip_atomic_fetch_add(ce_sum, bsum,
                                   __ATOMIC_RELAXED, __HIP_MEMORY_SCOPE_AGENT);
        }
    }

    // ------- fence-free ticket fan-in -------
    __syncthreads();
    asm volatile("s_waitcnt vmcnt(0)" ::: "memory");
    if (tid == 0) {
        int old = __hip_atomic_fetch_add(ticket, 1,
                                         __ATOMIC_RELAXED, __HIP_MEMORY_SCOPE_AGENT);
        lastFlag = (old == GRID_MAIN - 1);
    }
    __syncthreads();
    if (lastFlag) {
        float acc = 0.f;
        #pragma unroll
        for (int rr = 0; rr < 16; ++rr) {
            int row = rr * 256 + tid;
            unsigned int kx = __hip_atomic_load(&maxk[row], __ATOMIC_RELAXED,
                                                __HIP_MEMORY_SCOPE_AGENT);
            unsigned int kn = __hip_atomic_load(&mink[row], __ATOMIC_RELAXED,
                                                __HIP_MEMORY_SCOPE_AGENT);
            float pf = sqrtf(fmaxf(dec_max(kx), 1e-12f));
            float nf = sqrtf(fmaxf(dec_min(kn), 1e-12f));
            acc += fmaxf(pf - nf + MARGIN, 0.f);
        }
        // single-barrier wave reduce
        #pragma unroll
        for (int off = 1; off < 64; off <<= 1) acc += __shfl_xor(acc, off, 64);
        if (lane == 0) lg[0][wave] = acc;
        __syncthreads();
        if (tid == 0) {
            float ces = __hip_atomic_load(ce_sum, __ATOMIC_RELAXED,
                                          __HIP_MEMORY_SCOPE_AGENT);
            out[0] = ((lg[0][0] + lg[0][1] + lg[0][2] + lg[0][3]) + ces)
                     * (1.0f / BATCH);
        }
    }
}

extern "C" void kernel_launch(void* const* d_in, const int* in_sizes, int n_in,
                              void* d_out, int out_size, void* d_ws, size_t ws_size,
                              hipStream_t stream) {
    const float* emb    = (const float*)d_in[0];
    const int*   labels = (const int*)  d_in[1];
    const float* fcw    = (const float*)d_in[2];
    const float* fcb    = (const float*)d_in[3];
    float* out = (float*)d_out;

    char* ws = (char*)d_ws;
    int*   ticket       = (int*)(ws);                            // 4 B
    float* ce_sum       = (float*)(ws + 4);                      // 4 B
    unsigned int* maxk  = (unsigned int*)(ws + 8);               // 16 KB
    unsigned int* mink  = (unsigned int*)(ws + 8 + 16384);       // 16 KB

    // zero ticket + ce_sum + maxk + mink (graph-capturable memset node)
    hipMemsetAsync(ws, 0, 8 + 32768, stream);
    fused_kernel<<<GRID_MAIN, 256, 0, stream>>>(emb, labels, fcw, fcb,
                                                maxk, mink, ce_sum, ticket, out);
}